// Round 5
// baseline (704.632 us; speedup 1.0000x reference)
//
#include <hip/hip_runtime.h>
#include <hip/hip_bf16.h>

#define IN_DIM  512
#define HID     1024
#define OUT_DIM 512
#define BATCH   4096
#define T_STEPS 32

typedef __attribute__((ext_vector_type(8))) short bf16x8;
typedef __attribute__((ext_vector_type(4))) float f32x4;

__device__ inline void gload16(const void* g, void* l) {
  __builtin_amdgcn_global_load_lds(
      (const __attribute__((address_space(1))) void*)g,
      (__attribute__((address_space(3))) void*)l, 16, 0, 0);
}

// D[b][i] = sum_k A[b][k] * B[i][k], then relu(D + bias[i]).
// Tile: 128(b) x 128(i), BK=64, 8 waves (2x4), each 64x32. 1 block/CU.
// T4 counted vmcnt (4/tile/wave, depth-2, never 0 in loop) + raw s_barrier.
// T2 both-sides XOR swizzle: pre-swizzled GLOBAL source chunk, linear LDS
// dest (global_load_lds), XOR'd ds_read chunk. T5 setprio around MFMA.
// XCD swizzle: XCD x owns batch panels 4x..4x+3 across ALL launches, so the
// h^T panel written at step t is read from the same XCD's L2 at step t+1.
// A: [4096][K] bf16 row-major; B: [Ntot][K] bf16 row-major (k-contiguous)
// Cf: f32 transposed Cf[i*BATCH+b]; Cb: bf16 Cb[b*Nld+i] (may be null)
__global__ __launch_bounds__(512, 2) void gemm_bt_bias_relu(
    const __hip_bfloat16* __restrict__ A,
    const __hip_bfloat16* __restrict__ B,
    const float* __restrict__ bias,
    float* __restrict__ Cf,
    __hip_bfloat16* __restrict__ Cb,
    int K, int Nld, int nx)
{
  // bijective XCD swizzle (nwg % 8 == 0: 256 or 128)
  const int nwg = gridDim.x;
  const int q   = nwg >> 3;
  const int bid = blockIdx.x;
  const int swz = (bid & 7) * q + (bid >> 3);
  const int bxi = swz % nx;          // neuron-tile index
  const int byi = swz / nx;          // batch-panel index (4 per XCD, stable)
  const int brow = byi * 128;
  const int bcol = bxi * 128;

  const int tid  = threadIdx.x;
  const int lane = tid & 63;
  const int wid  = tid >> 6;               // 0..7
  const int wr   = wid >> 2, wc = wid & 3; // wave tile 64(b) x 32(i)
  const int l15  = lane & 15, l4 = lane >> 4;
  const int srow8  = lane >> 3;            // row within wave's 8-row stripe
  const int schunk = (lane & 7) ^ srow8;   // T2 stage-side pre-swizzle

  __shared__ __hip_bfloat16 Alds[2][128 * 64];  // 2 x 16 KB
  __shared__ __hip_bfloat16 Blds[2][128 * 64];  // 2 x 16 KB  (total 64 KB)

  f32x4 acc[4][2] = {};
  const int nt = K >> 6;   // 8 or 16

  // 4 gload16 per wave per tile (2 A rounds + 2 B rounds)
  auto stage = [&](int ti, int buf) {
    const int kt = ti << 6;
#pragma unroll
    for (int it = 0; it < 2; ++it) {
      const int rowbase = it * 64 + wid * 8;     // wave-uniform LDS row base
      gload16(A + (size_t)(brow + rowbase + srow8) * K + kt + schunk * 8,
              &Alds[buf][rowbase * 64]);
    }
#pragma unroll
    for (int it = 0; it < 2; ++it) {
      const int rowbase = it * 64 + wid * 8;
      gload16(B + (size_t)(bcol + rowbase + srow8) * K + kt + schunk * 8,
              &Blds[buf][rowbase * 64]);
    }
  };

  // ---- prologue: two tiles in flight ----
  stage(0, 0);
  stage(1, 1);

  const int rxor = l15 & 7;   // (row & 7) for every fragment row this lane reads

  for (int ti = 0; ti < nt; ++ti) {
    const int buf = ti & 1;
    // T4: wait only the current tile's 4 loads; next tile's stay in flight
    if (ti < nt - 1) {
      asm volatile("s_waitcnt vmcnt(4)" ::: "memory");
    } else {
      asm volatile("s_waitcnt vmcnt(0)" ::: "memory");
    }
    __builtin_amdgcn_s_barrier();
    __builtin_amdgcn_sched_barrier(0);

    __builtin_amdgcn_s_setprio(1);
#pragma unroll
    for (int ks = 0; ks < 2; ++ks) {
      bf16x8 af[4], bfr[2];
      const int cp = ((ks * 4 + l4) ^ rxor) * 8;   // T2 read-side XOR (16B chunks)
#pragma unroll
      for (int m = 0; m < 4; ++m)
        af[m] = *(const bf16x8*)&Alds[buf][(wr * 64 + m * 16 + l15) * 64 + cp];
#pragma unroll
      for (int n = 0; n < 2; ++n)
        bfr[n] = *(const bf16x8*)&Blds[buf][(wc * 32 + n * 16 + l15) * 64 + cp];
#pragma unroll
      for (int m = 0; m < 4; ++m)
#pragma unroll
        for (int n = 0; n < 2; ++n)
          acc[m][n] = __builtin_amdgcn_mfma_f32_16x16x32_bf16(af[m], bfr[n], acc[m][n], 0, 0, 0);
    }
    __builtin_amdgcn_s_setprio(0);

    asm volatile("s_waitcnt lgkmcnt(0)" ::: "memory");  // this wave's reads of buf done
    __builtin_amdgcn_sched_barrier(0);
    __builtin_amdgcn_s_barrier();                       // all waves done with buf
    __builtin_amdgcn_sched_barrier(0);
    if (ti < nt - 2) stage(ti + 2, buf);                // refill consumed buffer
  }

  // ---- epilogue: bias + relu, dual store ----
#pragma unroll
  for (int n = 0; n < 2; ++n) {
    const int i = bcol + wc * 32 + n * 16 + l15;
    const float bv = bias[i];
#pragma unroll
    for (int m = 0; m < 4; ++m) {
      const int b0 = brow + wr * 64 + m * 16 + l4 * 4;
      f32x4 v = acc[m][n];
      float4 o;
      o.x = fmaxf(v[0] + bv, 0.0f);
      o.y = fmaxf(v[1] + bv, 0.0f);
      o.z = fmaxf(v[2] + bv, 0.0f);
      o.w = fmaxf(v[3] + bv, 0.0f);
      *(float4*)(Cf + (size_t)i * BATCH + b0) = o;   // 64B sectors across l4 groups
      if (Cb) {
        Cb[(size_t)(b0 + 0) * Nld + i] = __float2bfloat16(o.x);
        Cb[(size_t)(b0 + 1) * Nld + i] = __float2bfloat16(o.y);
        Cb[(size_t)(b0 + 2) * Nld + i] = __float2bfloat16(o.z);
        Cb[(size_t)(b0 + 3) * Nld + i] = __float2bfloat16(o.w);
      }
    }
  }
}

// plain f32 -> bf16 convert (vectorized), n4 = count/4
__global__ __launch_bounds__(256) void f32_to_bf16(
    const float* __restrict__ in, __hip_bfloat16* __restrict__ out, int n4)
{
  int i = blockIdx.x * blockDim.x + threadIdx.x;
  if (i < n4) {
    float4 v = ((const float4*)in)[i];
    union { __hip_bfloat16 h[4]; ushort4 u; } p;
    p.h[0] = __float2bfloat16(v.x);
    p.h[1] = __float2bfloat16(v.y);
    p.h[2] = __float2bfloat16(v.z);
    p.h[3] = __float2bfloat16(v.w);
    ((ushort4*)out)[i] = p.u;
  }
}

// in[R][C] f32 -> out[C][R] bf16 (LDS 32x32 tile transpose)
__global__ __launch_bounds__(256) void transpose_f32_bf16(
    const float* __restrict__ in, __hip_bfloat16* __restrict__ out, int R, int C)
{
  __shared__ float tile[32][33];
  const int c0 = blockIdx.x * 32, r0 = blockIdx.y * 32;
  const int tx = threadIdx.x & 31, ty = threadIdx.x >> 5;
#pragma unroll
  for (int dy = 0; dy < 32; dy += 8)
    tile[ty + dy][tx] = in[(size_t)(r0 + ty + dy) * C + c0 + tx];
  __syncthreads();
#pragma unroll
  for (int dy = 0; dy < 32; dy += 8)
    out[(size_t)(c0 + ty + dy) * R + r0 + tx] = __float2bfloat16(tile[tx][ty + dy]);
}

extern "C" void kernel_launch(void* const* d_in, const int* in_sizes, int n_in,
                              void* d_out, int out_size, void* d_ws, size_t ws_size,
                              hipStream_t stream)
{
  const float* x     = (const float*)d_in[0];   // [512][4096]
  const float* W_in  = (const float*)d_in[1];   // [1024][512]
  const float* b_in  = (const float*)d_in[2];   // [1024]
  const float* W_rec = (const float*)d_in[3];   // [1024][1024]
  const float* b_rec = (const float*)d_in[4];   // [1024]
  const float* W_out = (const float*)d_in[5];   // [512][1024]
  const float* b_out = (const float*)d_in[6];   // [512]

  float* out0 = (float*)d_out;                        // [512][4096]
  float* itm  = out0 + (size_t)OUT_DIM * BATCH;       // [33][1024][4096]

  __hip_bfloat16* xT = (__hip_bfloat16*)d_ws;         // [4096][512]
  __hip_bfloat16* Wi = xT + (size_t)BATCH * IN_DIM;   // [1024][512]
  __hip_bfloat16* Wr = Wi + (size_t)HID * IN_DIM;     // [1024][1024]
  __hip_bfloat16* Wo = Wr + (size_t)HID * HID;        // [512][1024]
  __hip_bfloat16* h0 = Wo + (size_t)OUT_DIM * HID;    // [4096][1024]
  __hip_bfloat16* h1 = h0 + (size_t)BATCH * HID;      // [4096][1024]

  // input conversions
  transpose_f32_bf16<<<dim3(BATCH / 32, IN_DIM / 32), 256, 0, stream>>>(x, xT, IN_DIM, BATCH);
  {
    int n4 = HID * IN_DIM / 4;
    f32_to_bf16<<<(n4 + 255) / 256, 256, 0, stream>>>(W_in, Wi, n4);
  }
  {
    int n4 = HID * HID / 4;
    f32_to_bf16<<<(n4 + 255) / 256, 256, 0, stream>>>(W_rec, Wr, n4);
  }
  {
    int n4 = OUT_DIM * HID / 4;
    f32_to_bf16<<<(n4 + 255) / 256, 256, 0, stream>>>(W_out, Wo, n4);
  }

  // y0 = relu(W_in @ x + b_in): grid 256, nx = 1024/128 = 8
  gemm_bt_bias_relu<<<(HID / 128) * (BATCH / 128), 512, 0, stream>>>(
      xT, Wi, b_in, itm, h0, IN_DIM, HID, HID / 128);

  // 32 recurrent steps
  __hip_bfloat16* cur = h0;
  __hip_bfloat16* nxt = h1;
  for (int t = 0; t < T_STEPS; ++t) {
    float* dst = itm + (size_t)(t + 1) * HID * BATCH;
    gemm_bt_bias_relu<<<(HID / 128) * (BATCH / 128), 512, 0, stream>>>(
        cur, Wr, b_rec, dst, nxt, HID, HID, HID / 128);
    __hip_bfloat16* tmp = cur; cur = nxt; nxt = tmp;
  }

  // out = relu(W_out @ h_last + b_out): grid 128, nx = 512/128 = 4
  gemm_bt_bias_relu<<<(OUT_DIM / 128) * (BATCH / 128), 512, 0, stream>>>(
      cur, Wo, b_out, out0, (__hip_bfloat16*)nullptr, HID, 0, OUT_DIM / 128);
}

// Round 6
// 695.684 us; speedup vs baseline: 1.0129x; 1.0129x over previous
//
#include <hip/hip_runtime.h>
#include <hip/hip_bf16.h>

#define IN_DIM  512
#define HID     1024
#define OUT_DIM 512
#define BATCH   4096
#define T_STEPS 32

typedef __attribute__((ext_vector_type(8))) short bf16x8;
typedef __attribute__((ext_vector_type(4))) float f32x4;

__device__ inline void gload16(const void* g, void* l) {
  __builtin_amdgcn_global_load_lds(
      (const __attribute__((address_space(1))) void*)g,
      (__attribute__((address_space(3))) void*)l, 16, 0, 0);
}

// D[b][i] = sum_k A[b][k] * B[i][k], then relu(D + bias[i]).
// Tile: 128(b) x 64(i), BK=64, 4 waves each 64x32, 2 blocks/CU.
// Depth-3 rotating LDS buffer, ONE barrier per K-iter:
//   iter t: vmcnt(6) [tile t landed, tile t+1 in flight] -> s_barrier ->
//           stage(t+2) into buf consumed at t-1 -> ds_read+MFMA on buf[t].
// Safety: buf[(t+2)%3] was consumed at iter t-1; every wave's reads of it are
// data-depended by its iter-(t-1) MFMAs, which precede this barrier.
// T2 both-sides XOR swizzle (pre-swizzled global chunk + XOR'd ds_read,
// LDS linear for global_load_lds). T5 setprio around MFMA.
// A: [4096][K] bf16 row-major; B: [Ntot][K] bf16 row-major (k-contiguous)
// Cf: f32 transposed Cf[i*BATCH+b]; Cb: bf16 Cb[b*Nld+i] (may be null)
__global__ __launch_bounds__(256, 2) void gemm_bt_bias_relu(
    const __hip_bfloat16* __restrict__ A,
    const __hip_bfloat16* __restrict__ B,
    const float* __restrict__ bias,
    float* __restrict__ Cf,
    __hip_bfloat16* __restrict__ Cb,
    int K, int Nld)
{
  const int tid  = threadIdx.x;
  const int lane = tid & 63;
  const int wid  = tid >> 6;
  const int wr   = wid >> 1, wc = wid & 1;   // 2x2 waves: wave tile 64(b) x 32(i)
  const int brow = blockIdx.y * 128;
  const int bcol = blockIdx.x * 64;
  const int l15  = lane & 15, l4 = lane >> 4;
  const int srow = lane >> 3;
  const int schunk = (lane & 7) ^ (srow & 7);   // T2 stage-side pre-swizzle

  __shared__ __hip_bfloat16 Alds[3][128 * 64];  // 3 x 16 KB
  __shared__ __hip_bfloat16 Blds[3][64 * 64];   // 3 x  8 KB  (72 KB total)

  f32x4 acc[4][2] = {};
  const int nt = K >> 6;   // 8 or 16

  // 6 gload16 per wave per tile (4 A + 2 B) -> vmcnt steady-state = 6
  auto stage = [&](int ti, int buf) {
    const int kt = ti << 6;
#pragma unroll
    for (int it = 0; it < 4; ++it) {
      const int rowbase = it * 32 + wid * 8;           // wave-uniform LDS base
      gload16(A + (size_t)(brow + rowbase + srow) * K + kt + schunk * 8,
              &Alds[buf][rowbase * 64]);
    }
#pragma unroll
    for (int it = 0; it < 2; ++it) {
      const int rowbase = it * 32 + wid * 8;
      gload16(B + (size_t)(bcol + rowbase + srow) * K + kt + schunk * 8,
              &Blds[buf][rowbase * 64]);
    }
  };

  // ---- prologue: tiles 0,1 in flight ----
  stage(0, 0);
  stage(1, 1);

  const int rxor = l15 & 7;   // (row & 7) for every fragment row this lane reads

  int bufc = 0;
  for (int ti = 0; ti < nt; ++ti) {
    // T4: current tile's 6 loads done; next tile's 6 stay in flight
    if (ti < nt - 1) {
      asm volatile("s_waitcnt vmcnt(6)" ::: "memory");
    } else {
      asm volatile("s_waitcnt vmcnt(0)" ::: "memory");
    }
    __builtin_amdgcn_s_barrier();
    __builtin_amdgcn_sched_barrier(0);

    // refill the buffer consumed at iter t-1; its loads get 2 compute phases
    if (ti + 2 < nt) {
      const int bufs = bufc ? bufc - 1 : 2;   // (bufc + 2) % 3
      stage(ti + 2, bufs);
    }

    __builtin_amdgcn_s_setprio(1);
#pragma unroll
    for (int ks = 0; ks < 2; ++ks) {
      bf16x8 af[4], bfr[2];
      const int cp = ((ks * 4 + l4) ^ rxor) * 8;   // T2 read-side XOR (16B chunks)
#pragma unroll
      for (int m = 0; m < 4; ++m)
        af[m] = *(const bf16x8*)&Alds[bufc][(wr * 64 + m * 16 + l15) * 64 + cp];
#pragma unroll
      for (int n = 0; n < 2; ++n)
        bfr[n] = *(const bf16x8*)&Blds[bufc][(wc * 32 + n * 16 + l15) * 64 + cp];
#pragma unroll
      for (int m = 0; m < 4; ++m)
#pragma unroll
        for (int n = 0; n < 2; ++n)
          acc[m][n] = __builtin_amdgcn_mfma_f32_16x16x32_bf16(af[m], bfr[n], acc[m][n], 0, 0, 0);
    }
    __builtin_amdgcn_s_setprio(0);

    bufc = (bufc == 2) ? 0 : bufc + 1;
  }

  // ---- epilogue: bias + relu, dual store ----
#pragma unroll
  for (int n = 0; n < 2; ++n) {
    const int i = bcol + wc * 32 + n * 16 + l15;
    const float bv = bias[i];
#pragma unroll
    for (int m = 0; m < 4; ++m) {
      const int b0 = brow + wr * 64 + m * 16 + l4 * 4;
      f32x4 v = acc[m][n];
      float4 o;
      o.x = fmaxf(v[0] + bv, 0.0f);
      o.y = fmaxf(v[1] + bv, 0.0f);
      o.z = fmaxf(v[2] + bv, 0.0f);
      o.w = fmaxf(v[3] + bv, 0.0f);
      *(float4*)(Cf + (size_t)i * BATCH + b0) = o;
      if (Cb) {
        Cb[(size_t)(b0 + 0) * Nld + i] = __float2bfloat16(o.x);
        Cb[(size_t)(b0 + 1) * Nld + i] = __float2bfloat16(o.y);
        Cb[(size_t)(b0 + 2) * Nld + i] = __float2bfloat16(o.z);
        Cb[(size_t)(b0 + 3) * Nld + i] = __float2bfloat16(o.w);
      }
    }
  }
}

// plain f32 -> bf16 convert (vectorized), n4 = count/4
__global__ __launch_bounds__(256) void f32_to_bf16(
    const float* __restrict__ in, __hip_bfloat16* __restrict__ out, int n4)
{
  int i = blockIdx.x * blockDim.x + threadIdx.x;
  if (i < n4) {
    float4 v = ((const float4*)in)[i];
    union { __hip_bfloat16 h[4]; ushort4 u; } p;
    p.h[0] = __float2bfloat16(v.x);
    p.h[1] = __float2bfloat16(v.y);
    p.h[2] = __float2bfloat16(v.z);
    p.h[3] = __float2bfloat16(v.w);
    ((ushort4*)out)[i] = p.u;
  }
}

// in[R][C] f32 -> out[C][R] bf16 (LDS 32x32 tile transpose)
__global__ __launch_bounds__(256) void transpose_f32_bf16(
    const float* __restrict__ in, __hip_bfloat16* __restrict__ out, int R, int C)
{
  __shared__ float tile[32][33];
  const int c0 = blockIdx.x * 32, r0 = blockIdx.y * 32;
  const int tx = threadIdx.x & 31, ty = threadIdx.x >> 5;
#pragma unroll
  for (int dy = 0; dy < 32; dy += 8)
    tile[ty + dy][tx] = in[(size_t)(r0 + ty + dy) * C + c0 + tx];
  __syncthreads();
#pragma unroll
  for (int dy = 0; dy < 32; dy += 8)
    out[(size_t)(c0 + ty + dy) * R + r0 + tx] = __float2bfloat16(tile[tx][ty + dy]);
}

extern "C" void kernel_launch(void* const* d_in, const int* in_sizes, int n_in,
                              void* d_out, int out_size, void* d_ws, size_t ws_size,
                              hipStream_t stream)
{
  const float* x     = (const float*)d_in[0];   // [512][4096]
  const float* W_in  = (const float*)d_in[1];   // [1024][512]
  const float* b_in  = (const float*)d_in[2];   // [1024]
  const float* W_rec = (const float*)d_in[3];   // [1024][1024]
  const float* b_rec = (const float*)d_in[4];   // [1024]
  const float* W_out = (const float*)d_in[5];   // [512][1024]
  const float* b_out = (const float*)d_in[6];   // [512]

  float* out0 = (float*)d_out;                        // [512][4096]
  float* itm  = out0 + (size_t)OUT_DIM * BATCH;       // [33][1024][4096]

  __hip_bfloat16* xT = (__hip_bfloat16*)d_ws;         // [4096][512]
  __hip_bfloat16* Wi = xT + (size_t)BATCH * IN_DIM;   // [1024][512]
  __hip_bfloat16* Wr = Wi + (size_t)HID * IN_DIM;     // [1024][1024]
  __hip_bfloat16* Wo = Wr + (size_t)HID * HID;        // [512][1024]
  __hip_bfloat16* h0 = Wo + (size_t)OUT_DIM * HID;    // [4096][1024]
  __hip_bfloat16* h1 = h0 + (size_t)BATCH * HID;      // [4096][1024]

  // input conversions
  transpose_f32_bf16<<<dim3(BATCH / 32, IN_DIM / 32), 256, 0, stream>>>(x, xT, IN_DIM, BATCH);
  {
    int n4 = HID * IN_DIM / 4;
    f32_to_bf16<<<(n4 + 255) / 256, 256, 0, stream>>>(W_in, Wi, n4);
  }
  {
    int n4 = HID * HID / 4;
    f32_to_bf16<<<(n4 + 255) / 256, 256, 0, stream>>>(W_rec, Wr, n4);
  }
  {
    int n4 = OUT_DIM * HID / 4;
    f32_to_bf16<<<(n4 + 255) / 256, 256, 0, stream>>>(W_out, Wo, n4);
  }

  // y0 = relu(W_in @ x + b_in)
  gemm_bt_bias_relu<<<dim3(HID / 64, BATCH / 128), 256, 0, stream>>>(
      xT, Wi, b_in, itm, h0, IN_DIM, HID);

  // 32 recurrent steps
  __hip_bfloat16* cur = h0;
  __hip_bfloat16* nxt = h1;
  for (int t = 0; t < T_STEPS; ++t) {
    float* dst = itm + (size_t)(t + 1) * HID * BATCH;
    gemm_bt_bias_relu<<<dim3(HID / 64, BATCH / 128), 256, 0, stream>>>(
        cur, Wr, b_rec, dst, nxt, HID, HID);
    __hip_bfloat16* tmp = cur; cur = nxt; nxt = tmp;
  }

  // out = relu(W_out @ h_last + b_out)
  gemm_bt_bias_relu<<<dim3(OUT_DIM / 64, BATCH / 128), 256, 0, stream>>>(
      cur, Wo, b_out, out0, (__hip_bfloat16*)nullptr, HID, 0);
}

// Round 7
// 588.303 us; speedup vs baseline: 1.1977x; 1.1825x over previous
//
#include <hip/hip_runtime.h>
#include <hip/hip_bf16.h>

#define IN_DIM  512
#define HID     1024
#define OUT_DIM 512
#define BATCH   4096
#define T_STEPS 32

typedef __attribute__((ext_vector_type(8))) short bf16x8;
typedef __attribute__((ext_vector_type(4))) float f32x4;

__device__ inline void gload16(const void* g, void* l) {
  __builtin_amdgcn_global_load_lds(
      (const __attribute__((address_space(1))) void*)g,
      (__attribute__((address_space(3))) void*)l, 16, 0, 0);
}

// D[b][i] = sum_k A[b][k] * B[i][k], then relu(D + bias[i]).
// Tile: 128(b) x 64(i), BK=64, 4 waves each 64x32, 2 blocks/CU (R4 structure).
// T4 counted vmcnt depth-2 (vmcnt(6), never 0 in loop) + raw s_barrier pair.
// T2 both-sides XOR swizzle (pre-swizzled global chunk + XOR'd ds_read).
// T5 setprio around MFMA.
// NEW (R7): XCD-stable batch-panel swizzle — 1D grid, swz=(bid&7)*q+(bid>>3);
// XCD x owns byi in [4x,4x+4) on EVERY launch, so per-XCD L2 working set =
// A-slice (1MB) + W (2.1MB) < 4MB, and h^T panels written at step t are
// read from the same XCD's L2 at step t+1.
// NEW (R7): non-temporal store for Cf (itm is never re-read; don't evict L2).
// A: [4096][K] bf16 row-major; B: [Ntot][K] bf16 row-major (k-contiguous)
// Cf: f32 transposed Cf[i*BATCH+b]; Cb: bf16 Cb[b*Nld+i] (may be null)
__global__ __launch_bounds__(256, 2) void gemm_bt_bias_relu(
    const __hip_bfloat16* __restrict__ A,
    const __hip_bfloat16* __restrict__ B,
    const float* __restrict__ bias,
    float* __restrict__ Cf,
    __hip_bfloat16* __restrict__ Cb,
    int K, int Nld, int nx)
{
  // bijective XCD swizzle (nwg % 8 == 0: 512 or 256)
  const int nwg = gridDim.x;
  const int q   = nwg >> 3;
  const int bid = blockIdx.x;
  const int swz = (bid & 7) * q + (bid >> 3);
  const int bxi = swz % nx;          // neuron-tile index (all nx per XCD)
  const int byi = swz / nx;          // batch-panel index (4 per XCD, stable)
  const int brow = byi * 128;
  const int bcol = bxi * 64;

  const int tid  = threadIdx.x;
  const int lane = tid & 63;
  const int wid  = tid >> 6;
  const int wr   = wid >> 1, wc = wid & 1;   // 2x2 waves: wave tile 64(b) x 32(i)
  const int l15  = lane & 15, l4 = lane >> 4;
  const int srow = lane >> 3;
  const int schunk = (lane & 7) ^ (srow & 7);   // T2 stage-side pre-swizzle

  __shared__ __hip_bfloat16 Alds[2][128 * 64];  // 2 x 16 KB
  __shared__ __hip_bfloat16 Blds[2][64 * 64];   // 2 x  8 KB

  f32x4 acc[4][2] = {};
  const int nt = K >> 6;   // 8 or 16, always >= 2

  // 6 gload16 per wave per tile (4 A + 2 B) -> vmcnt granularity of 6
  auto stage = [&](int ti, int buf) {
    const int kt = ti << 6;
#pragma unroll
    for (int it = 0; it < 4; ++it) {
      const int rowbase = it * 32 + wid * 8;           // wave-uniform LDS base
      gload16(A + (size_t)(brow + rowbase + srow) * K + kt + schunk * 8,
              &Alds[buf][rowbase * 64]);
    }
#pragma unroll
    for (int it = 0; it < 2; ++it) {
      const int rowbase = it * 32 + wid * 8;
      gload16(B + (size_t)(bcol + rowbase + srow) * K + kt + schunk * 8,
              &Blds[buf][rowbase * 64]);
    }
  };

  // ---- prologue: two tiles in flight ----
  stage(0, 0);
  stage(1, 1);

  const int rxor = l15 & 7;   // (row & 7) for all fragment rows this lane reads

  for (int ti = 0; ti < nt; ++ti) {
    const int buf = ti & 1;
    // T4: wait current tile's 6 loads; keep next tile's 6 in flight
    if (ti < nt - 1) {
      asm volatile("s_waitcnt vmcnt(6)" ::: "memory");
    } else {
      asm volatile("s_waitcnt vmcnt(0)" ::: "memory");
    }
    __builtin_amdgcn_s_barrier();
    __builtin_amdgcn_sched_barrier(0);   // rule 18: pin ds_reads below the wait

    __builtin_amdgcn_s_setprio(1);
#pragma unroll
    for (int ks = 0; ks < 2; ++ks) {
      bf16x8 af[4], bfr[2];
      const int cp = ((ks * 4 + l4) ^ rxor) * 8;   // T2 read-side XOR (16B chunks)
#pragma unroll
      for (int m = 0; m < 4; ++m)
        af[m] = *(const bf16x8*)&Alds[buf][(wr * 64 + m * 16 + l15) * 64 + cp];
#pragma unroll
      for (int n = 0; n < 2; ++n)
        bfr[n] = *(const bf16x8*)&Blds[buf][(wc * 32 + n * 16 + l15) * 64 + cp];
#pragma unroll
      for (int m = 0; m < 4; ++m)
#pragma unroll
        for (int n = 0; n < 2; ++n)
          acc[m][n] = __builtin_amdgcn_mfma_f32_16x16x32_bf16(af[m], bfr[n], acc[m][n], 0, 0, 0);
    }
    __builtin_amdgcn_s_setprio(0);

    asm volatile("s_waitcnt lgkmcnt(0)" ::: "memory");  // all reads of buf done
    __builtin_amdgcn_sched_barrier(0);
    __builtin_amdgcn_s_barrier();                       // all waves done with buf
    __builtin_amdgcn_sched_barrier(0);                  // pin stage below barrier
    if (ti < nt - 2) stage(ti + 2, buf);                // refill consumed buffer
  }

  // ---- epilogue: bias + relu, dual store ----
#pragma unroll
  for (int n = 0; n < 2; ++n) {
    const int i = bcol + wc * 32 + n * 16 + l15;
    const float bv = bias[i];
#pragma unroll
    for (int m = 0; m < 4; ++m) {
      const int b0 = brow + wr * 64 + m * 16 + l4 * 4;
      f32x4 v = acc[m][n];
      f32x4 o;
      o[0] = fmaxf(v[0] + bv, 0.0f);
      o[1] = fmaxf(v[1] + bv, 0.0f);
      o[2] = fmaxf(v[2] + bv, 0.0f);
      o[3] = fmaxf(v[3] + bv, 0.0f);
      // itm/out is never re-read by the GEMM chain: bypass L2 (nt store)
      __builtin_nontemporal_store(o, (f32x4*)(Cf + (size_t)i * BATCH + b0));
      if (Cb) {
        // h^T IS re-read next step from this XCD's L2: keep cached stores
        Cb[(size_t)(b0 + 0) * Nld + i] = __float2bfloat16(o[0]);
        Cb[(size_t)(b0 + 1) * Nld + i] = __float2bfloat16(o[1]);
        Cb[(size_t)(b0 + 2) * Nld + i] = __float2bfloat16(o[2]);
        Cb[(size_t)(b0 + 3) * Nld + i] = __float2bfloat16(o[3]);
      }
    }
  }
}

// plain f32 -> bf16 convert (vectorized), n4 = count/4
__global__ __launch_bounds__(256) void f32_to_bf16(
    const float* __restrict__ in, __hip_bfloat16* __restrict__ out, int n4)
{
  int i = blockIdx.x * blockDim.x + threadIdx.x;
  if (i < n4) {
    float4 v = ((const float4*)in)[i];
    union { __hip_bfloat16 h[4]; ushort4 u; } p;
    p.h[0] = __float2bfloat16(v.x);
    p.h[1] = __float2bfloat16(v.y);
    p.h[2] = __float2bfloat16(v.z);
    p.h[3] = __float2bfloat16(v.w);
    ((ushort4*)out)[i] = p.u;
  }
}

// in[R][C] f32 -> out[C][R] bf16 (LDS 32x32 tile transpose)
__global__ __launch_bounds__(256) void transpose_f32_bf16(
    const float* __restrict__ in, __hip_bfloat16* __restrict__ out, int R, int C)
{
  __shared__ float tile[32][33];
  const int c0 = blockIdx.x * 32, r0 = blockIdx.y * 32;
  const int tx = threadIdx.x & 31, ty = threadIdx.x >> 5;
#pragma unroll
  for (int dy = 0; dy < 32; dy += 8)
    tile[ty + dy][tx] = in[(size_t)(r0 + ty + dy) * C + c0 + tx];
  __syncthreads();
#pragma unroll
  for (int dy = 0; dy < 32; dy += 8)
    out[(size_t)(c0 + ty + dy) * R + r0 + tx] = __float2bfloat16(tile[tx][ty + dy]);
}

extern "C" void kernel_launch(void* const* d_in, const int* in_sizes, int n_in,
                              void* d_out, int out_size, void* d_ws, size_t ws_size,
                              hipStream_t stream)
{
  const float* x     = (const float*)d_in[0];   // [512][4096]
  const float* W_in  = (const float*)d_in[1];   // [1024][512]
  const float* b_in  = (const float*)d_in[2];   // [1024]
  const float* W_rec = (const float*)d_in[3];   // [1024][1024]
  const float* b_rec = (const float*)d_in[4];   // [1024]
  const float* W_out = (const float*)d_in[5];   // [512][1024]
  const float* b_out = (const float*)d_in[6];   // [512]

  float* out0 = (float*)d_out;                        // [512][4096]
  float* itm  = out0 + (size_t)OUT_DIM * BATCH;       // [33][1024][4096]

  __hip_bfloat16* xT = (__hip_bfloat16*)d_ws;         // [4096][512]
  __hip_bfloat16* Wi = xT + (size_t)BATCH * IN_DIM;   // [1024][512]
  __hip_bfloat16* Wr = Wi + (size_t)HID * IN_DIM;     // [1024][1024]
  __hip_bfloat16* Wo = Wr + (size_t)HID * HID;        // [512][1024]
  __hip_bfloat16* h0 = Wo + (size_t)OUT_DIM * HID;    // [4096][1024]
  __hip_bfloat16* h1 = h0 + (size_t)BATCH * HID;      // [4096][1024]

  // input conversions
  transpose_f32_bf16<<<dim3(BATCH / 32, IN_DIM / 32), 256, 0, stream>>>(x, xT, IN_DIM, BATCH);
  {
    int n4 = HID * IN_DIM / 4;
    f32_to_bf16<<<(n4 + 255) / 256, 256, 0, stream>>>(W_in, Wi, n4);
  }
  {
    int n4 = HID * HID / 4;
    f32_to_bf16<<<(n4 + 255) / 256, 256, 0, stream>>>(W_rec, Wr, n4);
  }
  {
    int n4 = OUT_DIM * HID / 4;
    f32_to_bf16<<<(n4 + 255) / 256, 256, 0, stream>>>(W_out, Wo, n4);
  }

  // y0 = relu(W_in @ x + b_in): grid 512, nx = 16
  gemm_bt_bias_relu<<<(HID / 64) * (BATCH / 128), 256, 0, stream>>>(
      xT, Wi, b_in, itm, h0, IN_DIM, HID, HID / 64);

  // 32 recurrent steps
  __hip_bfloat16* cur = h0;
  __hip_bfloat16* nxt = h1;
  for (int t = 0; t < T_STEPS; ++t) {
    float* dst = itm + (size_t)(t + 1) * HID * BATCH;
    gemm_bt_bias_relu<<<(HID / 64) * (BATCH / 128), 256, 0, stream>>>(
        cur, Wr, b_rec, dst, nxt, HID, HID, HID / 64);
    __hip_bfloat16* tmp = cur; cur = nxt; nxt = tmp;
  }

  // out = relu(W_out @ h_last + b_out): grid 256, nx = 8
  gemm_bt_bias_relu<<<(OUT_DIM / 64) * (BATCH / 128), 256, 0, stream>>>(
      cur, Wo, b_out, out0, (__hip_bfloat16*)nullptr, HID, 0, OUT_DIM / 64);
}